// Round 1
// baseline (255.383 us; speedup 1.0000x reference)
//
#include <hip/hip_runtime.h>

#define BATCH   1024
#define ASZ     256
#define EDIM    200
#define RDIM    200
#define HDIM    400
#define ACTDIM  400   // E+R
#define INDIM   800   // E+H+R
#define NRELS   500

// ---------------------------------------------------------------------------
// K0: X_in[b] = [entity_emb[e[b]] ; H[b] ; relation_emb[q[b]]]
// ---------------------------------------------------------------------------
__global__ __launch_bounds__(256) void k_gather_concat(
    const int* __restrict__ e, const int* __restrict__ q,
    const float* __restrict__ H,
    const float* __restrict__ ent_emb, const float* __restrict__ rel_emb,
    float* __restrict__ Xin)
{
    int b = blockIdx.x;
    int t = threadIdx.x;
    const float* E  = ent_emb + (long)e[b] * EDIM;
    const float* Q  = rel_emb + (long)q[b] * RDIM;
    const float* Hr = H + (long)b * HDIM;
    float* X = Xin + (long)b * INDIM;
    for (int i = t; i < EDIM; i += 256) X[i] = E[i];
    for (int i = t; i < HDIM; i += 256) X[EDIM + i] = Hr[i];
    for (int i = t; i < RDIM; i += 256) X[EDIM + HDIM + i] = Q[i];
}

// ---------------------------------------------------------------------------
// Tiled fp32 GEMM: C[M,N] = op(A[M,K] @ B) + bias, optional relu.
// BT=0: B is [K,N] row-major.  BT=1: B is [N,K] row-major (C = A @ B^T).
// BM=BN=64, BK=16, 256 threads, 4x4 microtile. K must be a multiple of 4.
// ---------------------------------------------------------------------------
template<int RELU, int BT>
__global__ __launch_bounds__(256) void k_gemm(
    const float* __restrict__ A, const float* __restrict__ Bm,
    const float* __restrict__ bias, float* __restrict__ C,
    int M, int N, int K)
{
    __shared__ float As[16][64];
    __shared__ float Bs[16][64];

    int t  = threadIdx.x;
    int bn = blockIdx.x * 64;
    int bm = blockIdx.y * 64;

    int tm = t >> 4;   // 0..15
    int tn = t & 15;   // 0..15

    float acc[4][4];
#pragma unroll
    for (int i = 0; i < 4; ++i)
#pragma unroll
        for (int j = 0; j < 4; ++j) acc[i][j] = 0.f;

    int nk = (K + 15) / 16;
    for (int kt = 0; kt < nk; ++kt) {
        int k0 = kt * 16;

        // ---- load A tile: 64 x 16, float4 along K ----
        {
            int am = t >> 2;            // 0..63
            int ak = (t & 3) * 4;       // 0,4,8,12
            int gm = bm + am, gk = k0 + ak;
            float4 av = make_float4(0.f, 0.f, 0.f, 0.f);
            if (gm < M && gk + 4 <= K)
                av = *(const float4*)(A + (long)gm * K + gk);
            As[ak + 0][am] = av.x;
            As[ak + 1][am] = av.y;
            As[ak + 2][am] = av.z;
            As[ak + 3][am] = av.w;
        }
        // ---- load B tile: 16 x 64 ----
        if (BT == 0) {
            int bk = t >> 4;            // 0..15
            int bl = (t & 15) * 4;      // 0..60
            int gn = bn + bl, gk = k0 + bk;
            float4 bv = make_float4(0.f, 0.f, 0.f, 0.f);
            if (gk < K && gn + 4 <= N)
                bv = *(const float4*)(Bm + (long)gk * N + gn);
            Bs[bk][bl + 0] = bv.x;
            Bs[bk][bl + 1] = bv.y;
            Bs[bk][bl + 2] = bv.z;
            Bs[bk][bl + 3] = bv.w;
        } else {
            int bl = t >> 2;            // 0..63
            int bk = (t & 3) * 4;       // 0,4,8,12
            int gn = bn + bl, gk = k0 + bk;
            float4 bv = make_float4(0.f, 0.f, 0.f, 0.f);
            if (gn < N && gk + 4 <= K)
                bv = *(const float4*)(Bm + (long)gn * K + gk);
            Bs[bk + 0][bl] = bv.x;
            Bs[bk + 1][bl] = bv.y;
            Bs[bk + 2][bl] = bv.z;
            Bs[bk + 3][bl] = bv.w;
        }
        __syncthreads();

#pragma unroll
        for (int kk = 0; kk < 16; ++kk) {
            float a[4], bb[4];
#pragma unroll
            for (int i = 0; i < 4; ++i) a[i]  = As[kk][tm * 4 + i];
#pragma unroll
            for (int j = 0; j < 4; ++j) bb[j] = Bs[kk][tn * 4 + j];
#pragma unroll
            for (int i = 0; i < 4; ++i)
#pragma unroll
                for (int j = 0; j < 4; ++j)
                    acc[i][j] = fmaf(a[i], bb[j], acc[i][j]);
        }
        __syncthreads();
    }

#pragma unroll
    for (int i = 0; i < 4; ++i) {
        int gm = bm + tm * 4 + i;
        if (gm >= M) continue;
#pragma unroll
        for (int j = 0; j < 4; ++j) {
            int gn = bn + tn * 4 + j;
            if (gn >= N) continue;
            float v = acc[i][j] + (bias ? bias[gn] : 0.f);
            if (RELU) v = fmaxf(v, 0.f);
            C[(long)gm * N + gn] = v;
        }
    }
}

// ---------------------------------------------------------------------------
// K5: in-place row softmax over NRELS=500 (one block per row)
// ---------------------------------------------------------------------------
__global__ __launch_bounds__(256) void k_rel_softmax(float* __restrict__ R)
{
    int b = blockIdx.x, t = threadIdx.x;
    int wave = t >> 6, lane = t & 63;
    __shared__ float red[4];
    float* r = R + (long)b * NRELS;

    float m = -3.4e38f;
    for (int i = t; i < NRELS; i += 256) m = fmaxf(m, r[i]);
#pragma unroll
    for (int off = 32; off > 0; off >>= 1) m = fmaxf(m, __shfl_down(m, off));
    if (lane == 0) red[wave] = m;
    __syncthreads();
    m = fmaxf(fmaxf(red[0], red[1]), fmaxf(red[2], red[3]));
    __syncthreads();

    float s = 0.f;
    for (int i = t; i < NRELS; i += 256) {
        float ev = expf(r[i] - m);
        r[i] = ev;
        s += ev;
    }
#pragma unroll
    for (int off = 32; off > 0; off >>= 1) s += __shfl_down(s, off);
    if (lane == 0) red[wave] = s;
    __syncthreads();
    s = red[0] + red[1] + red[2] + red[3];
    float inv = 1.f / s;
    for (int i = t; i < NRELS; i += 256) r[i] *= inv;
}

// ---------------------------------------------------------------------------
// K6: scores (gathered 400-dim dots) + masked softmax + entropy
// One block per batch row; one wave per action (strided by 4 waves).
// ---------------------------------------------------------------------------
__global__ __launch_bounds__(256) void k_scores(
    const float* __restrict__ X2,
    const int* __restrict__ r_space, const int* __restrict__ e_space,
    const int* __restrict__ amask,
    const float* __restrict__ rel_emb, const float* __restrict__ ent_emb,
    float* __restrict__ out_dist, float* __restrict__ out_ent)
{
    int b = blockIdx.x, t = threadIdx.x;
    int wave = t >> 6, lane = t & 63;
    __shared__ __align__(16) float x2s[ACTDIM];
    __shared__ float sc[ASZ];
    __shared__ float red[4];

    for (int i = t; i < ACTDIM; i += 256) x2s[i] = X2[(long)b * ACTDIM + i];
    __syncthreads();

    const float4* xp = (const float4*)x2s;   // 100 float4

    for (int a = wave; a < ASZ; a += 4) {
        int r  = r_space[(long)b * ASZ + a];
        int ei = e_space[(long)b * ASZ + a];
        const float4* rp = (const float4*)(rel_emb + (long)r  * RDIM); // 50 f4
        const float4* ep = (const float4*)(ent_emb + (long)ei * EDIM); // 50 f4
        float s = 0.f;
        {
            int c4 = lane;                       // 0..63
            float4 v = (c4 < 50) ? rp[c4] : ep[c4 - 50];
            float4 x = xp[c4];
            s += v.x * x.x + v.y * x.y + v.z * x.z + v.w * x.w;
        }
        {
            int c4 = lane + 64;                  // 64..127
            if (c4 < 100) {
                float4 v = ep[c4 - 50];
                float4 x = xp[c4];
                s += v.x * x.x + v.y * x.y + v.z * x.z + v.w * x.w;
            }
        }
#pragma unroll
        for (int off = 32; off > 0; off >>= 1) s += __shfl_down(s, off);
        if (lane == 0) sc[a] = s;
    }
    __syncthreads();

    // masked softmax over 256 actions (one per thread)
    float v = sc[t] - (1.f - (float)amask[(long)b * ASZ + t]) * 1e31f;

    float m = v;
#pragma unroll
    for (int off = 32; off > 0; off >>= 1) m = fmaxf(m, __shfl_down(m, off));
    if (lane == 0) red[wave] = m;
    __syncthreads();
    m = fmaxf(fmaxf(red[0], red[1]), fmaxf(red[2], red[3]));
    __syncthreads();

    float ev = expf(v - m);
    float ssum = ev;
#pragma unroll
    for (int off = 32; off > 0; off >>= 1) ssum += __shfl_down(ssum, off);
    if (lane == 0) red[wave] = ssum;
    __syncthreads();
    ssum = red[0] + red[1] + red[2] + red[3];
    __syncthreads();

    float p = ev / ssum;
    out_dist[(long)b * ASZ + t] = p;

    float term = p * logf(p + 1e-20f);
#pragma unroll
    for (int off = 32; off > 0; off >>= 1) term += __shfl_down(term, off);
    if (lane == 0) red[wave] = term;
    __syncthreads();
    if (t == 0) out_ent[b] = -(red[0] + red[1] + red[2] + red[3]);
}

// ---------------------------------------------------------------------------
extern "C" void kernel_launch(void* const* d_in, const int* in_sizes, int n_in,
                              void* d_out, int out_size, void* d_ws, size_t ws_size,
                              hipStream_t stream)
{
    const int*   e       = (const int*)  d_in[0];
    const int*   q       = (const int*)  d_in[1];
    const float* H       = (const float*)d_in[2];
    const int*   r_space = (const int*)  d_in[3];
    const int*   e_space = (const int*)  d_in[4];
    const int*   amask   = (const int*)  d_in[5];
    const float* ent     = (const float*)d_in[6];
    const float* rel     = (const float*)d_in[7];
    const float* W1      = (const float*)d_in[8];
    const float* b1      = (const float*)d_in[9];
    const float* W2      = (const float*)d_in[10];
    const float* b2      = (const float*)d_in[11];
    const float* Watt    = (const float*)d_in[12];
    const float* batt    = (const float*)d_in[13];

    float* out      = (float*)d_out;
    float* out_dist = out;                              // [1024,256]
    float* out_ent  = out + (long)BATCH * ASZ;          // [1024]
    float* out_rel  = out_ent + BATCH;                  // [1024,500]

    char* ws = (char*)d_ws;
    float* Xin = (float*)(ws + 0);          // 1024*800*4 = 3,276,800
    float* X1  = (float*)(ws + 3276800);    // 1024*400*4 = 1,638,400
    float* X2  = (float*)(ws + 4915200);    // 1024*400*4 = 1,638,400
    float* T   = (float*)(ws + 6553600);    // 1024*200*4 =   819,200

    k_gather_concat<<<BATCH, 256, 0, stream>>>(e, q, H, ent, rel, Xin);

    // X1 = relu(Xin @ W1 + b1)       [1024,400] K=800
    k_gemm<1,0><<<dim3(7,16), 256, 0, stream>>>(Xin, W1, b1, X1, BATCH, ACTDIM, INDIM);
    // X2 = X1 @ W2 + b2              [1024,400] K=400
    k_gemm<0,0><<<dim3(7,16), 256, 0, stream>>>(X1, W2, b2, X2, BATCH, ACTDIM, ACTDIM);
    // T  = X2 @ W_att + b_att        [1024,200] K=400
    k_gemm<0,0><<<dim3(4,16), 256, 0, stream>>>(X2, Watt, batt, T, BATCH, RDIM, ACTDIM);
    // out_rel = T @ rel^T            [1024,500] K=200  (raw scores)
    k_gemm<0,1><<<dim3(8,16), 256, 0, stream>>>(T, rel, nullptr, out_rel, BATCH, NRELS, RDIM);

    k_rel_softmax<<<BATCH, 256, 0, stream>>>(out_rel);

    k_scores<<<BATCH, 256, 0, stream>>>(X2, r_space, e_space, amask, rel, ent,
                                        out_dist, out_ent);
}

// Round 2
// 200.744 us; speedup vs baseline: 1.2722x; 1.2722x over previous
//
#include <hip/hip_runtime.h>

#define BATCH   1024
#define ASZ     256
#define EDIM    200
#define RDIM    200
#define HDIM    400
#define ACTDIM  400   // E+R
#define INDIM   800   // E+H+R
#define NRELS   500

// ---------------------------------------------------------------------------
// K0: X_in[b] = [entity_emb[e[b]] ; H[b] ; relation_emb[q[b]]]
// ---------------------------------------------------------------------------
__global__ __launch_bounds__(256) void k_gather_concat(
    const int* __restrict__ e, const int* __restrict__ q,
    const float* __restrict__ H,
    const float* __restrict__ ent_emb, const float* __restrict__ rel_emb,
    float* __restrict__ Xin)
{
    int b = blockIdx.x;
    int t = threadIdx.x;
    const float* E  = ent_emb + (long)e[b] * EDIM;
    const float* Q  = rel_emb + (long)q[b] * RDIM;
    const float* Hr = H + (long)b * HDIM;
    float* X = Xin + (long)b * INDIM;
    for (int i = t; i < EDIM; i += 256) X[i] = E[i];
    for (int i = t; i < HDIM; i += 256) X[EDIM + i] = Hr[i];
    for (int i = t; i < RDIM; i += 256) X[EDIM + HDIM + i] = Q[i];
}

// ---------------------------------------------------------------------------
// Tiled fp32 GEMM: C[M,N] = op(A[M,K] @ B) + bias, optional relu.
// BT=0: B is [K,N] row-major.  BT=1: B is [N,K] row-major (C = A @ B^T).
// BM=BN=64, BK=16, 256 threads, 4x4 microtile, float4 LDS fragment reads.
// ---------------------------------------------------------------------------
template<int RELU, int BT>
__global__ __launch_bounds__(256) void k_gemm(
    const float* __restrict__ A, const float* __restrict__ Bm,
    const float* __restrict__ bias, float* __restrict__ C,
    int M, int N, int K)
{
    __shared__ __align__(16) float As[16][64];
    __shared__ __align__(16) float Bs[16][64];

    int t  = threadIdx.x;
    int bn = blockIdx.x * 64;
    int bm = blockIdx.y * 64;

    int tm = t >> 4;   // 0..15
    int tn = t & 15;   // 0..15

    float acc[4][4];
#pragma unroll
    for (int i = 0; i < 4; ++i)
#pragma unroll
        for (int j = 0; j < 4; ++j) acc[i][j] = 0.f;

    int nk = (K + 15) / 16;
    for (int kt = 0; kt < nk; ++kt) {
        int k0 = kt * 16;

        // ---- load A tile: 64 x 16, float4 along K ----
        {
            int am = t >> 2;            // 0..63
            int ak = (t & 3) * 4;       // 0,4,8,12
            int gm = bm + am, gk = k0 + ak;
            float4 av = make_float4(0.f, 0.f, 0.f, 0.f);
            if (gm < M && gk + 4 <= K)
                av = *(const float4*)(A + (long)gm * K + gk);
            As[ak + 0][am] = av.x;
            As[ak + 1][am] = av.y;
            As[ak + 2][am] = av.z;
            As[ak + 3][am] = av.w;
        }
        // ---- load B tile: 16 x 64 ----
        if (BT == 0) {
            int bk = t >> 4;            // 0..15
            int bl = (t & 15) * 4;      // 0..60
            int gn = bn + bl, gk = k0 + bk;
            float4 bv = make_float4(0.f, 0.f, 0.f, 0.f);
            if (gk < K && gn + 4 <= N)
                bv = *(const float4*)(Bm + (long)gk * N + gn);
            Bs[bk][bl + 0] = bv.x;
            Bs[bk][bl + 1] = bv.y;
            Bs[bk][bl + 2] = bv.z;
            Bs[bk][bl + 3] = bv.w;
        } else {
            int bl = t >> 2;            // 0..63
            int bk = (t & 3) * 4;       // 0,4,8,12
            int gn = bn + bl, gk = k0 + bk;
            float4 bv = make_float4(0.f, 0.f, 0.f, 0.f);
            if (gn < N && gk + 4 <= K)
                bv = *(const float4*)(Bm + (long)gn * K + gk);
            Bs[bk + 0][bl] = bv.x;
            Bs[bk + 1][bl] = bv.y;
            Bs[bk + 2][bl] = bv.z;
            Bs[bk + 3][bl] = bv.w;
        }
        __syncthreads();

#pragma unroll
        for (int kk = 0; kk < 16; ++kk) {
            float4 a4 = *(const float4*)&As[kk][tm * 4];
            float4 b4 = *(const float4*)&Bs[kk][tn * 4];
            float a[4] = {a4.x, a4.y, a4.z, a4.w};
            float bb[4] = {b4.x, b4.y, b4.z, b4.w};
#pragma unroll
            for (int i = 0; i < 4; ++i)
#pragma unroll
                for (int j = 0; j < 4; ++j)
                    acc[i][j] = fmaf(a[i], bb[j], acc[i][j]);
        }
        __syncthreads();
    }

#pragma unroll
    for (int i = 0; i < 4; ++i) {
        int gm = bm + tm * 4 + i;
        if (gm >= M) continue;
#pragma unroll
        for (int j = 0; j < 4; ++j) {
            int gn = bn + tn * 4 + j;
            if (gn >= N) continue;
            float v = acc[i][j] + (bias ? bias[gn] : 0.f);
            if (RELU) v = fmaxf(v, 0.f);
            C[(long)gm * N + gn] = v;
        }
    }
}

// ---------------------------------------------------------------------------
// K5: in-place row softmax over NRELS=500 (one block per row)
// ---------------------------------------------------------------------------
__global__ __launch_bounds__(256) void k_rel_softmax(float* __restrict__ R)
{
    int b = blockIdx.x, t = threadIdx.x;
    int wave = t >> 6, lane = t & 63;
    __shared__ float red[4];
    float* r = R + (long)b * NRELS;

    float m = -3.4e38f;
    for (int i = t; i < NRELS; i += 256) m = fmaxf(m, r[i]);
#pragma unroll
    for (int off = 32; off > 0; off >>= 1) m = fmaxf(m, __shfl_down(m, off));
    if (lane == 0) red[wave] = m;
    __syncthreads();
    m = fmaxf(fmaxf(red[0], red[1]), fmaxf(red[2], red[3]));
    __syncthreads();

    float s = 0.f;
    for (int i = t; i < NRELS; i += 256) {
        float ev = expf(r[i] - m);
        r[i] = ev;
        s += ev;
    }
#pragma unroll
    for (int off = 32; off > 0; off >>= 1) s += __shfl_down(s, off);
    if (lane == 0) red[wave] = s;
    __syncthreads();
    s = red[0] + red[1] + red[2] + red[3];
    float inv = 1.f / s;
    for (int i = t; i < NRELS; i += 256) r[i] *= inv;
}

// ---------------------------------------------------------------------------
// K6: scores + masked softmax + entropy.
// 512 threads = 8 waves per batch row; each wave owns 32 actions.
// Indices/mask preloaded into lanes; masked actions skipped entirely
// (reference fp32 semantics: dot - 1e31 == -1e31 exactly, since |dot| << ulp).
// 2 actions per iteration for memory-level parallelism.
// ---------------------------------------------------------------------------
__global__ __launch_bounds__(512) void k_scores(
    const float* __restrict__ X2,
    const int* __restrict__ r_space, const int* __restrict__ e_space,
    const int* __restrict__ amask,
    const float* __restrict__ rel_emb, const float* __restrict__ ent_emb,
    float* __restrict__ out_dist, float* __restrict__ out_ent)
{
    int b = blockIdx.x, t = threadIdx.x;
    int wave = t >> 6, lane = t & 63;
    __shared__ __align__(16) float x2s[ACTDIM];
    __shared__ float sc[ASZ];
    __shared__ float red[4];

    for (int i = t; i < ACTDIM; i += 512) x2s[i] = X2[(long)b * ACTDIM + i];

    // preload this wave's 32 action indices + mask into lanes 0..31
    int abase = wave * 32;
    int r_idx = 0, e_idx = 0, mk = 0;
    if (lane < 32) {
        long base = (long)b * ASZ + abase + lane;
        r_idx = r_space[base];
        e_idx = e_space[base];
        mk    = amask[base];
    }
    __syncthreads();

    const float4* xp = (const float4*)x2s;   // 100 float4
    float4 xA = xp[lane];                    // chunk A x-frag (c4 = lane)
    float4 xB = make_float4(0.f, 0.f, 0.f, 0.f);
    if (lane < 36) xB = xp[lane + 64];       // chunk B x-frag (c4 = lane+64)

#pragma unroll
    for (int i = 0; i < 16; ++i) {
        int a0 = 2 * i, a1 = 2 * i + 1;
        int m0 = __shfl(mk, a0),    m1 = __shfl(mk, a1);
        int r0 = __shfl(r_idx, a0), r1 = __shfl(r_idx, a1);
        int e0 = __shfl(e_idx, a0), e1 = __shfl(e_idx, a1);

        float s0 = 0.f, s1 = 0.f;
        if (m0) {   // wave-uniform branch
            const float4* rp = (const float4*)(rel_emb + (long)r0 * RDIM);
            const float4* ep = (const float4*)(ent_emb + (long)e0 * EDIM);
            float4 v0 = (lane < 50) ? rp[lane] : ep[lane - 50];
            s0 = v0.x * xA.x + v0.y * xA.y + v0.z * xA.z + v0.w * xA.w;
            if (lane < 36) {
                float4 v1 = ep[lane + 14];
                s0 += v1.x * xB.x + v1.y * xB.y + v1.z * xB.z + v1.w * xB.w;
            }
        }
        if (m1) {
            const float4* rp = (const float4*)(rel_emb + (long)r1 * RDIM);
            const float4* ep = (const float4*)(ent_emb + (long)e1 * EDIM);
            float4 v0 = (lane < 50) ? rp[lane] : ep[lane - 50];
            s1 = v0.x * xA.x + v0.y * xA.y + v0.z * xA.z + v0.w * xA.w;
            if (lane < 36) {
                float4 v1 = ep[lane + 14];
                s1 += v1.x * xB.x + v1.y * xB.y + v1.z * xB.z + v1.w * xB.w;
            }
        }
#pragma unroll
        for (int off = 32; off > 0; off >>= 1) {
            s0 += __shfl_xor(s0, off);
            s1 += __shfl_xor(s1, off);
        }
        if (lane == 0) {
            sc[abase + a0] = s0;
            sc[abase + a1] = s1;
        }
    }
    __syncthreads();

    // masked softmax over 256 actions: threads 0..255 own one action each;
    // waves 4..7 ride along through the barriers.
    float v = -3.4e38f;
    float evv = 0.f;
    if (t < ASZ) {
        int mt = amask[(long)b * ASZ + t];
        v = mt ? sc[t] : -1e31f;
    }

    float m = v;
#pragma unroll
    for (int off = 32; off > 0; off >>= 1) m = fmaxf(m, __shfl_xor(m, off));
    if (t < ASZ && lane == 0) red[wave] = m;
    __syncthreads();
    float mm = fmaxf(fmaxf(red[0], red[1]), fmaxf(red[2], red[3]));
    __syncthreads();

    if (t < ASZ) evv = expf(v - mm);
    float ss = evv;
#pragma unroll
    for (int off = 32; off > 0; off >>= 1) ss += __shfl_xor(ss, off);
    if (t < ASZ && lane == 0) red[wave] = ss;
    __syncthreads();
    float tot = red[0] + red[1] + red[2] + red[3];
    __syncthreads();

    float term = 0.f;
    if (t < ASZ) {
        float p = evv / tot;
        out_dist[(long)b * ASZ + t] = p;
        term = p * logf(p + 1e-20f);
    }
#pragma unroll
    for (int off = 32; off > 0; off >>= 1) term += __shfl_xor(term, off);
    if (t < ASZ && lane == 0) red[wave] = term;
    __syncthreads();
    if (t == 0) out_ent[b] = -(red[0] + red[1] + red[2] + red[3]);
}

// ---------------------------------------------------------------------------
extern "C" void kernel_launch(void* const* d_in, const int* in_sizes, int n_in,
                              void* d_out, int out_size, void* d_ws, size_t ws_size,
                              hipStream_t stream)
{
    const int*   e       = (const int*)  d_in[0];
    const int*   q       = (const int*)  d_in[1];
    const float* H       = (const float*)d_in[2];
    const int*   r_space = (const int*)  d_in[3];
    const int*   e_space = (const int*)  d_in[4];
    const int*   amask   = (const int*)  d_in[5];
    const float* ent     = (const float*)d_in[6];
    const float* rel     = (const float*)d_in[7];
    const float* W1      = (const float*)d_in[8];
    const float* b1      = (const float*)d_in[9];
    const float* W2      = (const float*)d_in[10];
    const float* b2      = (const float*)d_in[11];
    const float* Watt    = (const float*)d_in[12];
    const float* batt    = (const float*)d_in[13];

    float* out      = (float*)d_out;
    float* out_dist = out;                              // [1024,256]
    float* out_ent  = out + (long)BATCH * ASZ;          // [1024]
    float* out_rel  = out_ent + BATCH;                  // [1024,500]

    char* ws = (char*)d_ws;
    float* Xin = (float*)(ws + 0);          // 1024*800*4 = 3,276,800
    float* X1  = (float*)(ws + 3276800);    // 1024*400*4 = 1,638,400
    float* X2  = (float*)(ws + 4915200);    // 1024*400*4 = 1,638,400
    float* T   = (float*)(ws + 6553600);    // 1024*200*4 =   819,200

    k_gather_concat<<<BATCH, 256, 0, stream>>>(e, q, H, ent, rel, Xin);

    // X1 = relu(Xin @ W1 + b1)       [1024,400] K=800
    k_gemm<1,0><<<dim3(7,16), 256, 0, stream>>>(Xin, W1, b1, X1, BATCH, ACTDIM, INDIM);
    // X2 = X1 @ W2 + b2              [1024,400] K=400
    k_gemm<0,0><<<dim3(7,16), 256, 0, stream>>>(X1, W2, b2, X2, BATCH, ACTDIM, ACTDIM);
    // T  = X2 @ W_att + b_att        [1024,200] K=400
    k_gemm<0,0><<<dim3(4,16), 256, 0, stream>>>(X2, Watt, batt, T, BATCH, RDIM, ACTDIM);
    // out_rel = T @ rel^T            [1024,500] K=200  (raw scores)
    k_gemm<0,1><<<dim3(8,16), 256, 0, stream>>>(T, rel, nullptr, out_rel, BATCH, NRELS, RDIM);

    k_rel_softmax<<<BATCH, 256, 0, stream>>>(out_rel);

    k_scores<<<BATCH, 512, 0, stream>>>(X2, r_space, e_space, amask, rel, ent,
                                        out_dist, out_ent);
}

// Round 3
// 130.606 us; speedup vs baseline: 1.9554x; 1.5370x over previous
//
#include <hip/hip_runtime.h>

#define BATCH   1024
#define ASZ     256
#define EDIM    200
#define RDIM    200
#define HDIM    400
#define ACTDIM  400   // E+R
#define INDIM   800   // E+H+R
#define NRELS   500

#define BM 64
#define BN 64
#define BK 32

// ---------------------------------------------------------------------------
// K0: X_in[b] = [entity_emb[e[b]] ; H[b] ; relation_emb[q[b]]]  (float4)
// ---------------------------------------------------------------------------
__global__ __launch_bounds__(256) void k_gather_concat(
    const int* __restrict__ e, const int* __restrict__ q,
    const float* __restrict__ H,
    const float* __restrict__ ent_emb, const float* __restrict__ rel_emb,
    float* __restrict__ Xin)
{
    int b = blockIdx.x;
    int t = threadIdx.x;
    const float4* E4 = (const float4*)(ent_emb + (long)e[b] * EDIM);  // 50
    const float4* Q4 = (const float4*)(rel_emb + (long)q[b] * RDIM);  // 50
    const float4* H4 = (const float4*)(H + (long)b * HDIM);           // 100
    float4* X4 = (float4*)(Xin + (long)b * INDIM);                    // 200
    for (int i = t; i < 200; i += 256) {
        float4 v = (i < 50) ? E4[i] : (i < 150) ? H4[i - 50] : Q4[i - 150];
        X4[i] = v;
    }
}

// ---------------------------------------------------------------------------
// Split-K tiled fp32 GEMM.  C[M,N] = op(A[M,K] @ B) (+bias, relu if nks==1).
// BT=0: B is [K,N].  BT=1: B is [N,K] (C = A @ B^T).
// Grid: (ceil(N/BN), ceil(M/BM), KS). If KS>1, raw partials go to Cp[ks] slabs.
// 256 threads, 4x4 microtile, BK=32, double-buffered LDS.
// ---------------------------------------------------------------------------
template<int RELU, int BT>
__global__ __launch_bounds__(256) void k_gemm(
    const float* __restrict__ A, const float* __restrict__ Bm,
    const float* __restrict__ bias,
    float* __restrict__ C, float* __restrict__ Cp,
    int M, int N, int K, int kslice)
{
    __shared__ __align__(16) float As[2][BK][BM];
    __shared__ __align__(16) float Bs[2][BK][BN];

    const int t   = threadIdx.x;
    const int bn  = blockIdx.x * BN;
    const int bm  = blockIdx.y * BM;
    const int ks  = blockIdx.z;
    const int nks = gridDim.z;
    const int kbeg = ks * kslice;
    const int kend = min(K, kbeg + kslice);
    const int nk   = (kend - kbeg + BK - 1) / BK;

    // loader geometry
    const int ar  = t >> 3;            // 0..31  (rows ar and ar+32)
    const int ak4 = (t & 7) * 4;       // 0,4,...,28
    const int bkr = t >> 4;            // 0..15  (k rows bkr, bkr+16)  [BT=0]
    const int bnc = (t & 15) * 4;      // 0..60                        [BT=0]

    float4 a0, a1, b0, b1;

    auto fetch = [&](int kt) {
        const int k0 = kbeg + kt * BK;
        {
            int gm0 = bm + ar, gm1 = bm + ar + 32;
            int gk = k0 + ak4;
            bool kok = (gk + 4 <= kend);
            a0 = (kok && gm0 < M) ? *(const float4*)(A + (long)gm0 * K + gk)
                                  : make_float4(0.f, 0.f, 0.f, 0.f);
            a1 = (kok && gm1 < M) ? *(const float4*)(A + (long)gm1 * K + gk)
                                  : make_float4(0.f, 0.f, 0.f, 0.f);
        }
        if (BT == 0) {
            int gk0 = k0 + bkr, gk1 = k0 + bkr + 16;
            int gn = bn + bnc;
            bool nok = (gn + 4 <= N);
            b0 = (nok && gk0 < kend) ? *(const float4*)(Bm + (long)gk0 * N + gn)
                                     : make_float4(0.f, 0.f, 0.f, 0.f);
            b1 = (nok && gk1 < kend) ? *(const float4*)(Bm + (long)gk1 * N + gn)
                                     : make_float4(0.f, 0.f, 0.f, 0.f);
        } else {
            int gn0 = bn + ar, gn1 = bn + ar + 32;
            int gk = k0 + ak4;
            bool kok = (gk + 4 <= kend);
            b0 = (kok && gn0 < N) ? *(const float4*)(Bm + (long)gn0 * K + gk)
                                  : make_float4(0.f, 0.f, 0.f, 0.f);
            b1 = (kok && gn1 < N) ? *(const float4*)(Bm + (long)gn1 * K + gk)
                                  : make_float4(0.f, 0.f, 0.f, 0.f);
        }
    };

    auto stage = [&](int buf) {
        As[buf][ak4 + 0][ar] = a0.x;  As[buf][ak4 + 1][ar] = a0.y;
        As[buf][ak4 + 2][ar] = a0.z;  As[buf][ak4 + 3][ar] = a0.w;
        As[buf][ak4 + 0][ar + 32] = a1.x;  As[buf][ak4 + 1][ar + 32] = a1.y;
        As[buf][ak4 + 2][ar + 32] = a1.z;  As[buf][ak4 + 3][ar + 32] = a1.w;
        if (BT == 0) {
            *(float4*)&Bs[buf][bkr][bnc]      = b0;
            *(float4*)&Bs[buf][bkr + 16][bnc] = b1;
        } else {
            Bs[buf][ak4 + 0][ar] = b0.x;  Bs[buf][ak4 + 1][ar] = b0.y;
            Bs[buf][ak4 + 2][ar] = b0.z;  Bs[buf][ak4 + 3][ar] = b0.w;
            Bs[buf][ak4 + 0][ar + 32] = b1.x;  Bs[buf][ak4 + 1][ar + 32] = b1.y;
            Bs[buf][ak4 + 2][ar + 32] = b1.z;  Bs[buf][ak4 + 3][ar + 32] = b1.w;
        }
    };

    float acc[4][4];
#pragma unroll
    for (int i = 0; i < 4; ++i)
#pragma unroll
        for (int j = 0; j < 4; ++j) acc[i][j] = 0.f;

    const int tm = t >> 4;   // 0..15
    const int tn = t & 15;   // 0..15

    fetch(0);
    stage(0);
    __syncthreads();

    for (int kt = 0; kt < nk; ++kt) {
        const int cur = kt & 1;
        if (kt + 1 < nk) fetch(kt + 1);

#pragma unroll
        for (int kk = 0; kk < BK; ++kk) {
            const float4 a4 = *(const float4*)&As[cur][kk][tm * 4];
            const float4 b4 = *(const float4*)&Bs[cur][kk][tn * 4];
            acc[0][0] = fmaf(a4.x, b4.x, acc[0][0]);
            acc[0][1] = fmaf(a4.x, b4.y, acc[0][1]);
            acc[0][2] = fmaf(a4.x, b4.z, acc[0][2]);
            acc[0][3] = fmaf(a4.x, b4.w, acc[0][3]);
            acc[1][0] = fmaf(a4.y, b4.x, acc[1][0]);
            acc[1][1] = fmaf(a4.y, b4.y, acc[1][1]);
            acc[1][2] = fmaf(a4.y, b4.z, acc[1][2]);
            acc[1][3] = fmaf(a4.y, b4.w, acc[1][3]);
            acc[2][0] = fmaf(a4.z, b4.x, acc[2][0]);
            acc[2][1] = fmaf(a4.z, b4.y, acc[2][1]);
            acc[2][2] = fmaf(a4.z, b4.z, acc[2][2]);
            acc[2][3] = fmaf(a4.z, b4.w, acc[2][3]);
            acc[3][0] = fmaf(a4.w, b4.x, acc[3][0]);
            acc[3][1] = fmaf(a4.w, b4.y, acc[3][1]);
            acc[3][2] = fmaf(a4.w, b4.z, acc[3][2]);
            acc[3][3] = fmaf(a4.w, b4.w, acc[3][3]);
        }

        if (kt + 1 < nk) {
            __syncthreads();
            stage(cur ^ 1);
            __syncthreads();
        }
    }

    const int gn0 = bn + tn * 4;
    if (nks == 1) {
#pragma unroll
        for (int i = 0; i < 4; ++i) {
            int gm = bm + tm * 4 + i;
            if (gm >= M || gn0 >= N) continue;
            float4 v = make_float4(acc[i][0], acc[i][1], acc[i][2], acc[i][3]);
            if (bias) {
                float4 bb = *(const float4*)(bias + gn0);
                v.x += bb.x; v.y += bb.y; v.z += bb.z; v.w += bb.w;
            }
            if (RELU) {
                v.x = fmaxf(v.x, 0.f); v.y = fmaxf(v.y, 0.f);
                v.z = fmaxf(v.z, 0.f); v.w = fmaxf(v.w, 0.f);
            }
            *(float4*)(C + (long)gm * N + gn0) = v;
        }
    } else {
        float* dst = Cp + (long)ks * M * N;
#pragma unroll
        for (int i = 0; i < 4; ++i) {
            int gm = bm + tm * 4 + i;
            if (gm >= M || gn0 >= N) continue;
            float4 v = make_float4(acc[i][0], acc[i][1], acc[i][2], acc[i][3]);
            *(float4*)(dst + (long)gm * N + gn0) = v;
        }
    }
}

// ---------------------------------------------------------------------------
// Split-K reduce: C[m,n] = op(sum_ks Cp[ks][m][n] + bias[n])
// ---------------------------------------------------------------------------
template<int RELU, int HASBIAS>
__global__ __launch_bounds__(128) void k_reduce(
    const float* __restrict__ Cp, const float* __restrict__ bias,
    float* __restrict__ C, int M, int N, int nks)
{
    int m = blockIdx.x;
    int nf4 = N >> 2;
    for (int f = threadIdx.x; f < nf4; f += 128) {
        long off = (long)m * N + f * 4;
        float4 s = *(const float4*)(Cp + off);
        for (int ks = 1; ks < nks; ++ks) {
            float4 v = *(const float4*)(Cp + (long)ks * M * N + off);
            s.x += v.x; s.y += v.y; s.z += v.z; s.w += v.w;
        }
        if (HASBIAS) {
            float4 bb = *(const float4*)(bias + f * 4);
            s.x += bb.x; s.y += bb.y; s.z += bb.z; s.w += bb.w;
        }
        if (RELU) {
            s.x = fmaxf(s.x, 0.f); s.y = fmaxf(s.y, 0.f);
            s.z = fmaxf(s.z, 0.f); s.w = fmaxf(s.w, 0.f);
        }
        *(float4*)(C + off) = s;
    }
}

// ---------------------------------------------------------------------------
// K5: in-place row softmax over NRELS=500 (one block per row)
// ---------------------------------------------------------------------------
__global__ __launch_bounds__(256) void k_rel_softmax(float* __restrict__ R)
{
    int b = blockIdx.x, t = threadIdx.x;
    int wave = t >> 6, lane = t & 63;
    __shared__ float red[4];
    float* r = R + (long)b * NRELS;

    float m = -3.4e38f;
    for (int i = t; i < NRELS; i += 256) m = fmaxf(m, r[i]);
#pragma unroll
    for (int off = 32; off > 0; off >>= 1) m = fmaxf(m, __shfl_down(m, off));
    if (lane == 0) red[wave] = m;
    __syncthreads();
    m = fmaxf(fmaxf(red[0], red[1]), fmaxf(red[2], red[3]));
    __syncthreads();

    float s = 0.f;
    for (int i = t; i < NRELS; i += 256) {
        float ev = expf(r[i] - m);
        r[i] = ev;
        s += ev;
    }
#pragma unroll
    for (int off = 32; off > 0; off >>= 1) s += __shfl_down(s, off);
    if (lane == 0) red[wave] = s;
    __syncthreads();
    s = red[0] + red[1] + red[2] + red[3];
    float inv = 1.f / s;
    for (int i = t; i < NRELS; i += 256) r[i] *= inv;
}

// ---------------------------------------------------------------------------
// K6: scores + masked softmax + entropy.  512 threads = 8 waves per row;
// each wave owns 32 actions; masked actions skipped (dot-1e31 == -1e31 in
// fp32 since |dot| << ulp(1e31)); 2 actions/iter for MLP.
// ---------------------------------------------------------------------------
__global__ __launch_bounds__(512) void k_scores(
    const float* __restrict__ X2,
    const int* __restrict__ r_space, const int* __restrict__ e_space,
    const int* __restrict__ amask,
    const float* __restrict__ rel_emb, const float* __restrict__ ent_emb,
    float* __restrict__ out_dist, float* __restrict__ out_ent)
{
    int b = blockIdx.x, t = threadIdx.x;
    int wave = t >> 6, lane = t & 63;
    __shared__ __align__(16) float x2s[ACTDIM];
    __shared__ float sc[ASZ];
    __shared__ float red[4];

    for (int i = t; i < ACTDIM; i += 512) x2s[i] = X2[(long)b * ACTDIM + i];

    int abase = wave * 32;
    int r_idx = 0, e_idx = 0, mk = 0;
    if (lane < 32) {
        long base = (long)b * ASZ + abase + lane;
        r_idx = r_space[base];
        e_idx = e_space[base];
        mk    = amask[base];
    }
    __syncthreads();

    const float4* xp = (const float4*)x2s;   // 100 float4
    float4 xA = xp[lane];
    float4 xB = make_float4(0.f, 0.f, 0.f, 0.f);
    if (lane < 36) xB = xp[lane + 64];

#pragma unroll
    for (int i = 0; i < 16; ++i) {
        int a0 = 2 * i, a1 = 2 * i + 1;
        int m0 = __shfl(mk, a0),    m1 = __shfl(mk, a1);
        int r0 = __shfl(r_idx, a0), r1 = __shfl(r_idx, a1);
        int e0 = __shfl(e_idx, a0), e1 = __shfl(e_idx, a1);

        float s0 = 0.f, s1 = 0.f;
        if (m0) {
            const float4* rp = (const float4*)(rel_emb + (long)r0 * RDIM);
            const float4* ep = (const float4*)(ent_emb + (long)e0 * EDIM);
            float4 v0 = (lane < 50) ? rp[lane] : ep[lane - 50];
            s0 = v0.x * xA.x + v0.y * xA.y + v0.z * xA.z + v0.w * xA.w;
            if (lane < 36) {
                float4 v1 = ep[lane + 14];
                s0 += v1.x * xB.x + v1.y * xB.y + v1.z * xB.z + v1.w * xB.w;
            }
        }
        if (m1) {
            const float4* rp = (const float4*)(rel_emb + (long)r1 * RDIM);
            const float4* ep = (const float4*)(ent_emb + (long)e1 * EDIM);
            float4 v0 = (lane < 50) ? rp[lane] : ep[lane - 50];
            s1 = v0.x * xA.x + v0.y * xA.y + v0.z * xA.z + v0.w * xA.w;
            if (lane < 36) {
                float4 v1 = ep[lane + 14];
                s1 += v1.x * xB.x + v1.y * xB.y + v1.z * xB.z + v1.w * xB.w;
            }
        }
#pragma unroll
        for (int off = 32; off > 0; off >>= 1) {
            s0 += __shfl_xor(s0, off);
            s1 += __shfl_xor(s1, off);
        }
        if (lane == 0) {
            sc[abase + a0] = s0;
            sc[abase + a1] = s1;
        }
    }
    __syncthreads();

    float v = -3.4e38f;
    float evv = 0.f;
    if (t < ASZ) {
        int mt = amask[(long)b * ASZ + t];
        v = mt ? sc[t] : -1e31f;
    }

    float m = v;
#pragma unroll
    for (int off = 32; off > 0; off >>= 1) m = fmaxf(m, __shfl_xor(m, off));
    if (t < ASZ && lane == 0) red[wave] = m;
    __syncthreads();
    float mm = fmaxf(fmaxf(red[0], red[1]), fmaxf(red[2], red[3]));
    __syncthreads();

    if (t < ASZ) evv = expf(v - mm);
    float ss = evv;
#pragma unroll
    for (int off = 32; off > 0; off >>= 1) ss += __shfl_xor(ss, off);
    if (t < ASZ && lane == 0) red[wave] = ss;
    __syncthreads();
    float tot = red[0] + red[1] + red[2] + red[3];
    __syncthreads();

    float term = 0.f;
    if (t < ASZ) {
        float p = evv / tot;
        out_dist[(long)b * ASZ + t] = p;
        term = p * logf(p + 1e-20f);
    }
#pragma unroll
    for (int off = 32; off > 0; off >>= 1) term += __shfl_xor(term, off);
    if (t < ASZ && lane == 0) red[wave] = term;
    __syncthreads();
    if (t == 0) out_ent[b] = -(red[0] + red[1] + red[2] + red[3]);
}

// ---------------------------------------------------------------------------
extern "C" void kernel_launch(void* const* d_in, const int* in_sizes, int n_in,
                              void* d_out, int out_size, void* d_ws, size_t ws_size,
                              hipStream_t stream)
{
    const int*   e       = (const int*)  d_in[0];
    const int*   q       = (const int*)  d_in[1];
    const float* H       = (const float*)d_in[2];
    const int*   r_space = (const int*)  d_in[3];
    const int*   e_space = (const int*)  d_in[4];
    const int*   amask   = (const int*)  d_in[5];
    const float* ent     = (const float*)d_in[6];
    const float* rel     = (const float*)d_in[7];
    const float* W1      = (const float*)d_in[8];
    const float* b1      = (const float*)d_in[9];
    const float* W2      = (const float*)d_in[10];
    const float* b2      = (const float*)d_in[11];
    const float* Watt    = (const float*)d_in[12];
    const float* batt    = (const float*)d_in[13];

    float* out      = (float*)d_out;
    float* out_dist = out;                              // [1024,256]
    float* out_ent  = out + (long)BATCH * ASZ;          // [1024]
    float* out_rel  = out_ent + BATCH;                  // [1024,500]

    char* ws = (char*)d_ws;
    float* Xin = (float*)(ws + 0);          // 3,276,800
    float* X1  = (float*)(ws + 3276800);    // 1,638,400
    float* X2  = (float*)(ws + 4915200);    // 1,638,400
    float* T   = (float*)(ws + 6553600);    //   819,200
    float* Cp  = (float*)(ws + 7372800);    // up to 6,553,600 (split-K partials)

    const bool sk = ws_size >= (size_t)13926400;   // partials fit?
    const int ks1 = sk ? 4 : 1, ks2 = sk ? 4 : 1, ks3 = sk ? 4 : 1, ks4 = sk ? 2 : 1;

    k_gather_concat<<<BATCH, 256, 0, stream>>>(e, q, H, ent, rel, Xin);

    // X1 = relu(Xin @ W1 + b1)   [1024,400] K=800
    k_gemm<1,0><<<dim3(7,16,ks1), 256, 0, stream>>>(Xin, W1, b1, X1, Cp,
                                                    BATCH, ACTDIM, INDIM, INDIM/ks1);
    if (sk) k_reduce<1,1><<<BATCH, 128, 0, stream>>>(Cp, b1, X1, BATCH, ACTDIM, ks1);

    // X2 = X1 @ W2 + b2          [1024,400] K=400
    k_gemm<0,0><<<dim3(7,16,ks2), 256, 0, stream>>>(X1, W2, b2, X2, Cp,
                                                    BATCH, ACTDIM, ACTDIM, ACTDIM/ks2);
    if (sk) k_reduce<0,1><<<BATCH, 128, 0, stream>>>(Cp, b2, X2, BATCH, ACTDIM, ks2);

    // T = X2 @ W_att + b_att     [1024,200] K=400
    k_gemm<0,0><<<dim3(4,16,ks3), 256, 0, stream>>>(X2, Watt, batt, T, Cp,
                                                    BATCH, RDIM, ACTDIM, ACTDIM/ks3);
    if (sk) k_reduce<0,1><<<BATCH, 128, 0, stream>>>(Cp, batt, T, BATCH, RDIM, ks3);

    // out_rel = T @ rel^T        [1024,500] K=200  (raw scores)
    k_gemm<0,1><<<dim3(8,16,ks4), 256, 0, stream>>>(T, rel, nullptr, out_rel, Cp,
                                                    BATCH, NRELS, RDIM, RDIM/ks4);
    if (sk) k_reduce<0,0><<<BATCH, 128, 0, stream>>>(Cp, nullptr, out_rel, BATCH, NRELS, ks4);

    k_rel_softmax<<<BATCH, 256, 0, stream>>>(out_rel);

    k_scores<<<BATCH, 512, 0, stream>>>(X2, r_space, e_space, amask, rel, ent,
                                        out_dist, out_ent);
}